// Round 11
// baseline (116.900 us; speedup 1.0000x reference)
//
#include <hip/hip_runtime.h>

// ---------------------------------------------------------------------------
// CostVolume fused kernel, R11: R10 + weight packs hoisted to NAMED registers
// (no bf16x8 arrays -> no scratch; rule-#20 diagnosis of R5/R7/R9 failures:
// VGPR stayed 128 while scratch exploded = array-to-scratch, not reg pressure).
// W11/W21 (stage 1) and W30A/W31 (stage 2) live in 64 VGPR of named frags,
// consumed via macro-expanded MFMA sequences. W20 stays LDS-per-use.
// LDS 78,848 B => 2 blocks/CU, 8 waves/CU.
// ---------------------------------------------------------------------------

typedef __attribute__((ext_vector_type(8))) short   short8;
typedef __attribute__((ext_vector_type(8))) __bf16  bf16x8;
typedef __attribute__((ext_vector_type(4))) float   f32x4;
typedef __attribute__((ext_vector_type(4))) float   float4v;
typedef __attribute__((ext_vector_type(2))) unsigned int uint2v;
typedef __attribute__((ext_vector_type(4))) unsigned int uint4v;

#define S_LEN 8192
#define TPB   256
#define LOG2E 1.4426950408889634f

// ---- workspace byte offsets (written by pack_weights) ----
#define WSO_L11   0
#define WSO_L20   8192
#define WSO_L21   24576
#define WSO_L30A  32768
#define WSO_L31   40960
#define WS_WF1    49152
#define WS_WF2    57344
#define WS_W30B   65536
#define WS_W30C   73728
#define WS_F32    81920   // 1344 f32: x-combos (6*192) + we1/ee/ge (3*64)

// ---- LDS byte offsets ----
#define OFF_W     0       // 32 KB: s1 W11@0 W20@8192 W21@24576; s2 W30A@0 W31@24576
#define OFF_OUTB  8192    // [32][64] f32 swizzled, overlays W20 slot (stage 2)
#define OFF_ACT   32768   // 4 waves x (myA 4K + myB 4K); phase A: F1B@+0, F2B@+4096
#define OFF_A1B   65536   // [32][64] bf16 swz: a1 (stage1) -> v1 (stage2)
#define OFF_A2B   69632   // [32][64] bf16 swz: a2 (stage1) -> v2 (stage2)
#define OFF_AGGB  73728   // [32][64] bf16 swz
#define OFF_X1    77824   // [32][4] f32
#define OFF_X2    78336
#define LDS_TOTAL 78848

__device__ __forceinline__ unsigned short f2bf(float f){
  unsigned int u = __float_as_uint(f);
  u += 0x7fffu + ((u >> 16) & 1u);
  return (unsigned short)(u >> 16);
}
__device__ __forceinline__ float bf2f(unsigned short h){
  return __uint_as_float(((unsigned int)h) << 16);
}
__device__ __forceinline__ unsigned cvtpk(float lo, float hi){
  unsigned r;
  asm("v_cvt_pk_bf16_f32 %0, %1, %2" : "=v"(r) : "v"(lo), "v"(hi));
  return r;
}
__device__ __forceinline__ float exp2a(float x){
  float r; asm("v_exp_f32 %0, %1" : "=v"(r) : "v"(x)); return r;
}

// swizzled bf16 [32][64]: byte = (r*128 + c*2) ^ ((r&7)<<4)
__device__ __forceinline__ bf16x8 ldsA(const char* base, int r, int k){
  short8 a = *(const short8*)(base + ((((r << 6) + k) << 1) ^ ((r & 7) << 4)));
  return __builtin_bit_cast(bf16x8, a);
}
__device__ __forceinline__ void stBF(char* base, int r, int c, float v){
  *(unsigned short*)(base + ((((r << 6) + c) << 1) ^ ((r & 7) << 4))) = f2bf(v);
}
__device__ __forceinline__ float ldBF(const char* base, int r, int c){
  return bf2f(*(const unsigned short*)(base + ((((r << 6) + c) << 1) ^ ((r & 7) << 4))));
}
__device__ __forceinline__ void stBF4(char* base, int r, int c4, float4v v){
  uint2v u; u.x = cvtpk(v.x, v.y); u.y = cvtpk(v.z, v.w);
  *(uint2v*)(base + ((((r << 6) + c4) << 1) ^ ((r & 7) << 4))) = u;
}
// read 4 consecutive bf16 (c4 % 4 == 0) -> f32x4
__device__ __forceinline__ float4v ldBF4(const char* base, int r, int c4){
  uint2v u = *(const uint2v*)(base + ((((r << 6) + c4) << 1) ^ ((r & 7) << 4)));
  float4v f;
  f.x = bf2f((unsigned short)(u.x & 0xffffu));
  f.y = bf2f((unsigned short)(u.x >> 16));
  f.z = bf2f((unsigned short)(u.y & 0xffffu));
  f.w = bf2f((unsigned short)(u.y >> 16));
  return f;
}
// OUTB f32 [32][64], idx ^= (p&7)<<2
__device__ __forceinline__ int outb_idx(int p, int ch){
  return ((p << 6) + ch) ^ ((p & 7) << 2);
}
// one weight fragment from a pack (LDS or global)
__device__ __forceinline__ bf16x8 ldw(const char* Bp, int u, int lane){
  return __builtin_bit_cast(bf16x8, *(const short8*)(Bp + (u * 64 + lane) * 16));
}

#define MF(A,B,C) __builtin_amdgcn_mfma_f32_16x16x32_bf16(A,B,C,0,0,0)

// named 8-fragment pack (NO arrays -> guaranteed registers)
#define DECL8(P) bf16x8 P##_0,P##_1,P##_2,P##_3,P##_4,P##_5,P##_6,P##_7
#define LOAD8(P, Bp) do{ const char* _b=(Bp); \
  P##_0=ldw(_b,0,lane); P##_1=ldw(_b,1,lane); P##_2=ldw(_b,2,lane); P##_3=ldw(_b,3,lane); \
  P##_4=ldw(_b,4,lane); P##_5=ldw(_b,5,lane); P##_6=ldw(_b,6,lane); P##_7=ldw(_b,7,lane); }while(0)

// ch-major GEMM with named pack P as A-operand (W), acts from LDS.
// Mirrors gemm_chL ordering: kb0 -> P0..3, kb1 -> P4..7.
#define GEMM_CH(acc, act, P) do{ \
  bf16x8 _f0 = ldsA(act, l15,      kg); \
  bf16x8 _f1 = ldsA(act, 16 + l15, kg); \
  acc[0][0]=MF(P##_0,_f0,acc[0][0]); acc[0][1]=MF(P##_1,_f0,acc[0][1]); \
  acc[0][2]=MF(P##_2,_f0,acc[0][2]); acc[0][3]=MF(P##_3,_f0,acc[0][3]); \
  acc[1][0]=MF(P##_0,_f1,acc[1][0]); acc[1][1]=MF(P##_1,_f1,acc[1][1]); \
  acc[1][2]=MF(P##_2,_f1,acc[1][2]); acc[1][3]=MF(P##_3,_f1,acc[1][3]); \
  bf16x8 _f2 = ldsA(act, l15,      32 + kg); \
  bf16x8 _f3 = ldsA(act, 16 + l15, 32 + kg); \
  acc[0][0]=MF(P##_4,_f2,acc[0][0]); acc[0][1]=MF(P##_5,_f2,acc[0][1]); \
  acc[0][2]=MF(P##_6,_f2,acc[0][2]); acc[0][3]=MF(P##_7,_f2,acc[0][3]); \
  acc[1][0]=MF(P##_4,_f3,acc[1][0]); acc[1][1]=MF(P##_5,_f3,acc[1][1]); \
  acc[1][2]=MF(P##_6,_f3,acc[1][2]); acc[1][3]=MF(P##_7,_f3,acc[1][3]); }while(0)

// pair-major GEMM with named pack P as B-operand (W), acts from LDS.
// Mirrors gemm32_k64B: t,kb loops; B index kb*4+cb.
#define GEMM_PM(acc2, act, P) do{ \
  bf16x8 _a0 = ldsA(act, l15, kg); \
  acc2[0][0]=MF(_a0,P##_0,acc2[0][0]); acc2[0][1]=MF(_a0,P##_1,acc2[0][1]); \
  acc2[0][2]=MF(_a0,P##_2,acc2[0][2]); acc2[0][3]=MF(_a0,P##_3,acc2[0][3]); \
  bf16x8 _a1 = ldsA(act, l15, 32 + kg); \
  acc2[0][0]=MF(_a1,P##_4,acc2[0][0]); acc2[0][1]=MF(_a1,P##_5,acc2[0][1]); \
  acc2[0][2]=MF(_a1,P##_6,acc2[0][2]); acc2[0][3]=MF(_a1,P##_7,acc2[0][3]); \
  bf16x8 _a2 = ldsA(act, 16 + l15, kg); \
  acc2[1][0]=MF(_a2,P##_0,acc2[1][0]); acc2[1][1]=MF(_a2,P##_1,acc2[1][1]); \
  acc2[1][2]=MF(_a2,P##_2,acc2[1][2]); acc2[1][3]=MF(_a2,P##_3,acc2[1][3]); \
  bf16x8 _a3 = ldsA(act, 16 + l15, 32 + kg); \
  acc2[1][0]=MF(_a3,P##_4,acc2[1][0]); acc2[1][1]=MF(_a3,P##_5,acc2[1][1]); \
  acc2[1][2]=MF(_a3,P##_6,acc2[1][2]); acc2[1][3]=MF(_a3,P##_7,acc2[1][3]); }while(0)

// pair-major K=64 GEMM over 16 rows (precompute), B-pack read per-use
__device__ __forceinline__ void gemm_k64(f32x4 acc[4], const char* Asrc,
                                         const char* Bp, int rbase, int lane){
  const int r  = rbase + (lane & 15);
  const int kgl = (lane >> 4) << 3;
#pragma unroll
  for (int kb = 0; kb < 2; ++kb){
    bf16x8 a = ldsA(Asrc, r, kb * 32 + kgl);
#pragma unroll
    for (int cb = 0; cb < 4; ++cb){
      short8 braw = *(const short8*)(Bp + (((kb << 2) + cb) * 64 + lane) * 16);
      acc[cb] = MF(a, __builtin_bit_cast(bf16x8, braw), acc[cb]);
    }
  }
}

// ch-major K=64 GEMM, W from LDS pack per-use (W20 only)
__device__ __forceinline__ void gemm_chL(f32x4 acc[2][4], const char* act,
                                         const char* Wp, int l15, int kg, int lane){
#pragma unroll
  for (int kb = 0; kb < 2; ++kb){
    bf16x8 W0 = ldw(Wp, kb*4 + 0, lane);
    bf16x8 W1 = ldw(Wp, kb*4 + 1, lane);
    bf16x8 W2 = ldw(Wp, kb*4 + 2, lane);
    bf16x8 W3 = ldw(Wp, kb*4 + 3, lane);
#pragma unroll
    for (int nb = 0; nb < 2; ++nb){
      bf16x8 bfrag = ldsA(act, nb * 16 + l15, kb * 32 + kg);
      acc[nb][0] = MF(W0, bfrag, acc[nb][0]);
      acc[nb][1] = MF(W1, bfrag, acc[nb][1]);
      acc[nb][2] = MF(W2, bfrag, acc[nb][2]);
      acc[nb][3] = MF(W3, bfrag, acc[nb][3]);
    }
  }
}

// ch-major epilogue: relu(acc) -> 8B-vectorized bf16 stores (bias already in acc)
__device__ __forceinline__ void store_chR(char* dst, f32x4 acc[2][4],
                                          int l15, int g){
#pragma unroll
  for (int nb = 0; nb < 2; ++nb){
    const int row = nb * 16 + l15;
    const int rb  = row << 7;
    const int swz = (row & 7) << 4;
#pragma unroll
    for (int mb = 0; mb < 4; ++mb){
      f32x4 z = acc[nb][mb];
      z.x=fmaxf(z.x,0.f); z.y=fmaxf(z.y,0.f); z.z=fmaxf(z.z,0.f); z.w=fmaxf(z.w,0.f);
      uint2v u; u.x = cvtpk(z.x, z.y); u.y = cvtpk(z.z, z.w);
      *(uint2v*)(dst + (rb + ((mb * 32 + g * 8) ^ swz))) = u;
    }
  }
}

__device__ __forceinline__ float red_sum(float x){
  x += __shfl_xor(x, 16, 64);
  x += __shfl_xor(x, 32, 64);
  return x;
}

__global__ void pack_weights(const float* __restrict__ w10, const float* __restrict__ w11,
                             const float* __restrict__ wx1, const float* __restrict__ wx2,
                             const float* __restrict__ w20, const float* __restrict__ w21,
                             const float* __restrict__ w30, const float* __restrict__ w31,
                             unsigned char* __restrict__ ws)
{
  for (int i = blockIdx.x * blockDim.x + threadIdx.x; i < 42304;
       i += gridDim.x * blockDim.x){
    if (i < 40960){
      const float* src; int stride, coff, e;
      if      (i <  4096){ src = w11; stride =  64; coff =   0; e = i;         }
      else if (i < 12288){ src = w20; stride = 128; coff =   0; e = i -  4096; }
      else if (i < 16384){ src = w21; stride =  64; coff =   0; e = i - 12288; }
      else if (i < 20480){ src = w30; stride = 192; coff =   0; e = i - 16384; }
      else if (i < 24576){ src = w31; stride =  64; coff =   0; e = i - 20480; }
      else if (i < 28672){ src = w10; stride = 138; coff =  10; e = i - 24576; }
      else if (i < 32768){ src = w10; stride = 138; coff =  74; e = i - 28672; }
      else if (i < 36864){ src = w30; stride = 192; coff =  64; e = i - 32768; }
      else               { src = w30; stride = 192; coff = 128; e = i - 36864; }
      int j = e & 7, lane = (e >> 3) & 63, cb = (e >> 9) & 3, kb = e >> 11;
      int k = kb * 32 + ((lane >> 4) << 3) + j;
      int o = cb * 16 + (lane & 15);
      float val = src[o * stride + coff + k];
      // pre-scale logit-layer weights by log2(e): exp(x)=exp2(x*LOG2E)
      if ((i >= 12288 && i < 16384) || (i >= 20480 && i < 24576)) val *= LOG2E;
      ((unsigned short*)ws)[i] = f2bf(val);
    } else {
      int f = i - 40960; float v;
      if (f < 1152){
        int grp = f / 192, rem = f % 192, d = rem >> 6, o = rem & 63;
        if      (grp == 0) v = w10[o*138 + d]     - w10[o*138 + 6 + d];
        else if (grp == 1) v = w10[o*138 + 3 + d] + w10[o*138 + 6 + d];
        else if (grp == 2) v = wx1[o*10 + d]      - wx1[o*10 + 6 + d];
        else if (grp == 3) v = wx1[o*10 + 3 + d]  + wx1[o*10 + 6 + d];
        else if (grp == 4) v = wx2[o*10 + d]      - wx2[o*10 + 6 + d];
        else               v = wx2[o*10 + 3 + d]  + wx2[o*10 + 6 + d];
      }
      else if (f < 1216) v = w10[(f - 1152)*138 + 9];
      else if (f < 1280) v = wx1[(f - 1216)*10  + 9];
      else               v = wx2[(f - 1280)*10  + 9];
      ((float*)(ws + WS_F32))[f] = v;
    }
  }
}

__global__ __launch_bounds__(TPB, 2) void cvkernel(
    const float* __restrict__ xyz1, const float* __restrict__ feat1,
    const float* __restrict__ xyz2, const float* __restrict__ feat2,
    const float* __restrict__ b10v, const float* __restrict__ bx1v,
    const float* __restrict__ b11v, const float* __restrict__ b20v,
    const float* __restrict__ b21v, const float* __restrict__ bx2v,
    const float* __restrict__ b30v, const float* __restrict__ b31v,
    const char*  __restrict__ ws,   float* __restrict__ out)
{
  extern __shared__ __align__(16) char smem[];
  const int tid  = threadIdx.x;
  const int lane = tid & 63;
  const int wave = tid >> 6;
  const int l15  = lane & 15;
  const int lg   = lane >> 4;
  const int kg   = lg << 3;
  const int l31  = lane & 31;
  const int tile = blockIdx.x;
  const int b    = tile >> 8;
  const int s0   = (tile & 255) << 5;

  float* x1   = (float*)(smem + OFF_X1);
  float* x2   = (float*)(smem + OFF_X2);
  char*  a1B  = smem + OFF_A1B;
  char*  a2B  = smem + OFF_A2B;
  char*  aggB = smem + OFF_AGGB;
  char*  wlds = smem + OFF_W;
  float* outb = (float*)(smem + OFF_OUTB);
  const float* cw = (const float*)(ws + WS_F32);

  char* myA = smem + OFF_ACT + wave * 8192;
  char* myB = myA + 4096;

  // ======== phase A: stage weights (32 KB), inputs, X ========
  { const uint4v* src = (const uint4v*)ws;            // L11+L20+L21
    uint4v*       dst = (uint4v*)wlds;
    for (int i = tid; i < 2048; i += TPB) dst[i] = src[i]; }
  if (tid < 32){
#pragma unroll
    for (int d = 0; d < 3; ++d) x1[tid*4+d] = xyz1[(b*3+d)*S_LEN + s0 + tid];
    x1[tid*4+3] = 0.f;
  } else if (tid < 64){
    int p = tid - 32;
#pragma unroll
    for (int d = 0; d < 3; ++d) x2[p*4+d] = xyz2[(b*3+d)*S_LEN + s0 + p];
    x2[p*4+3] = 0.f;
  }
  for (int i = tid; i < 2048; i += TPB){                // F1B/F2B into ACT region
    int ch = i >> 5, p = i & 31;
    stBF(smem + OFF_ACT,        p, ch, feat1[(b*64+ch)*S_LEN + s0 + p]);
    stBF(smem + OFF_ACT + 4096, p, ch, feat2[(b*64+ch)*S_LEN + s0 + p]);
  }
  __syncthreads();

  // per-point precompute: a1 = Wf1*f1 + x-part, a2 = Wf2*f2 + x-part (bf16 out)
  {
    const char* Ab  = (wave < 2) ? (smem + OFF_ACT) : (smem + OFF_ACT + 4096);
    const char* Bg  = ws + ((wave < 2) ? WS_WF1 : WS_WF2);
    char* dstB      = (wave < 2) ? a1B : a2B;
    const float* cc = (wave < 2) ? cw : cw + 192;
    const float* xs = (wave < 2) ? x1 : x2;
    const int rt    = wave & 1;
    f32x4 acc[4];
#pragma unroll
    for (int cb = 0; cb < 4; ++cb) acc[cb] = (f32x4){0.f,0.f,0.f,0.f};
    gemm_k64(acc, Ab, Bg, rt * 16, lane);
#pragma unroll
    for (int cb = 0; cb < 4; ++cb){
      int col = (cb << 4) + l15;
      float c0 = cc[col], c1 = cc[64+col], c2 = cc[128+col];
#pragma unroll
      for (int v = 0; v < 4; ++v){
        int row = rt*16 + (lg << 2) + v;
        float val = acc[cb][v] + c0*xs[row*4] + c1*xs[row*4+1] + c2*xs[row*4+2];
        stBF(dstB, row, col, val);
      }
    }
  }
  __syncthreads();

  const int myc4 = l15 << 2;
  const int gc4  = lg << 2;

  // ================= stage 1 =================
  {
    const float4v we4 = *(const float4v*)(cw + 1152 + myc4);
    const float4v ee4 = *(const float4v*)(cw + 1216 + myc4);
    const float4v b04 = *(const float4v*)(b10v + myc4);
    const float4v b14 = *(const float4v*)(bx1v + myc4);
    const float4v C1a = *(const float4v*)(cw + 384 + myc4);
    const float4v C1b = *(const float4v*)(cw + 448 + myc4);
    const float4v C1c = *(const float4v*)(cw + 512 + myc4);
    const float4v C2a = *(const float4v*)(cw + 576 + myc4);
    const float4v C2b = *(const float4v*)(cw + 640 + myc4);
    const float4v C2c = *(const float4v*)(cw + 704 + myc4);
    float4v b11f4[4], b20f4[4];
#pragma unroll
    for (int mb = 0; mb < 4; ++mb){
      b11f4[mb] = *(const float4v*)(b11v + mb*16 + gc4);
      b20f4[mb] = *(const float4v*)(b20v + mb*16 + gc4);
    }
    float b21r[4];
#pragma unroll
    for (int cb = 0; cb < 4; ++cb) b21r[cb] = b21v[cb*16 + l15] * LOG2E;

    // hoist W11 + W21 into NAMED registers (64 VGPR, no arrays)
    DECL8(W11r); DECL8(W21r);
    LOAD8(W11r, wlds + 0);
    LOAD8(W21r, wlds + 24576);

    for (int cc = 0; cc < 8; ++cc){
      const int p  = wave*8 + cc;
      const float px = x1[p*4], py = x1[p*4+1], pz = x1[p*4+2];
      // each lane computes euc for q = lane&31; consumers shfl it
      float euR;
      { float dx = x2[l31*4]-px, dy = x2[l31*4+1]-py, dz = x2[l31*4+2]-pz;
        euR = sqrtf(dx*dx + dy*dy + dz*dz + 1e-20f); }
      const float4v hbase = ldBF4(a1B, p, myc4) + b04;
      const float4v ebase = C1a*px + C1b*py + C1c*pz + b14;
      // build h1 -> myA, e -> myB
#pragma unroll
      for (int it = 0; it < 8; ++it){
        int q = it*4 + lg;
        float qx = x2[q*4], qy = x2[q*4+1], qz = x2[q*4+2];
        float eu = __shfl(euR, q, 64);
        float4v A2 = ldBF4(a2B, q, myc4);
        float4v hv = hbase + A2 + we4*eu;
        float4v ev = ebase + C2a*qx + C2b*qy + C2c*qz + ee4*eu;
        hv.x = fmaxf(hv.x,0.f); hv.y = fmaxf(hv.y,0.f); hv.z = fmaxf(hv.z,0.f); hv.w = fmaxf(hv.w,0.f);
        ev.x = fmaxf(ev.x,0.f); ev.y = fmaxf(ev.y,0.f); ev.z = fmaxf(ev.z,0.f); ev.w = fmaxf(ev.w,0.f);
        stBF4(myA, q, myc4, hv);
        stBF4(myB, q, myc4, ev);
      }
      // mlp1_1 (ch-major): h2 = relu(W11*h1 + b11) -> myA (bias in acc init)
      f32x4 acc[2][4];
#pragma unroll
      for (int nb = 0; nb < 2; ++nb)
#pragma unroll
        for (int mb = 0; mb < 4; ++mb) acc[nb][mb] = b11f4[mb];
      __builtin_amdgcn_s_setprio(1);
      GEMM_CH(acc, myA, W11r);
      __builtin_amdgcn_s_setprio(0);
      store_chR(myA, acc, l15, lg);
      // mlp2_0 (ch-major, K=128): [e(myB); h2(myA)] -> myB (bias in acc init)
#pragma unroll
      for (int nb = 0; nb < 2; ++nb)
#pragma unroll
        for (int mb = 0; mb < 4; ++mb) acc[nb][mb] = b20f4[mb];
      __builtin_amdgcn_s_setprio(1);
      gemm_chL(acc, myB, wlds + 8192,  l15, kg, lane);
      gemm_chL(acc, myA, wlds + 16384, l15, kg, lane);
      __builtin_amdgcn_s_setprio(0);
      store_chR(myB, acc, l15, lg);
      // mlp2_1 (pair-major): logits (bias in acc init, pre-scaled by log2e)
      f32x4 acc2[2][4];
#pragma unroll
      for (int t = 0; t < 2; ++t)
#pragma unroll
        for (int cb = 0; cb < 4; ++cb)
          acc2[t][cb] = (f32x4){b21r[cb], b21r[cb], b21r[cb], b21r[cb]};
      __builtin_amdgcn_s_setprio(1);
      GEMM_PM(acc2, myB, W21r);
      __builtin_amdgcn_s_setprio(0);
      // no-max softmax over 32 q + aggregation (h2 from myA); logits >= 0 bounded
      float den[4] = {0.f,0.f,0.f,0.f}, num[4] = {0.f,0.f,0.f,0.f};
#pragma unroll
      for (int t = 0; t < 2; ++t)
#pragma unroll
        for (int cb = 0; cb < 4; ++cb)
#pragma unroll
          for (int v = 0; v < 4; ++v){
            float e = exp2a(fmaxf(acc2[t][cb][v], 0.f));
            den[cb] += e;
            num[cb] += e * ldBF(myA, t*16 + (lg<<2) + v, (cb<<4) + l15);
          }
#pragma unroll
      for (int cb = 0; cb < 4; ++cb){ den[cb] = red_sum(den[cb]); num[cb] = red_sum(num[cb]); }
      {
        float nv = (lg==0)?num[0]:((lg==1)?num[1]:((lg==2)?num[2]:num[3]));
        float dv = (lg==0)?den[0]:((lg==1)?den[1]:((lg==2)?den[2]:den[3]));
        stBF(aggB, p, (lg<<4) + l15, nv / dv);   // all 64 lanes: 64 channels
      }
    }
  }
  __syncthreads();

  // ======== phase C: restage f1, swap W packs, v1/v2 precompute ========
  for (int i = tid; i < 2048; i += TPB){                // f1 -> ACT+0
    int ch = i >> 5, p = i & 31;
    stBF(smem + OFF_ACT, p, ch, feat1[(b*64+ch)*S_LEN + s0 + p]);
  }
  { const uint4v* sA = (const uint4v*)(ws + WSO_L30A);  // W30A -> slot 0
    const uint4v* sB = (const uint4v*)(ws + WSO_L31);   // W31  -> slot 24576
    uint4v* dA = (uint4v*)(wlds);
    uint4v* dB = (uint4v*)(wlds + 24576);
    for (int i = tid; i < 512; i += TPB){ dA[i] = sA[i]; dB[i] = sB[i]; } }
  __syncthreads();
  {
    const char* Ab = (wave < 2) ? (smem + OFF_ACT) : aggB;
    const char* Bg = ws + ((wave < 2) ? WS_W30B : WS_W30C);
    char* dstB     = (wave < 2) ? a1B : a2B;            // v1 / v2
    const int rt   = wave & 1;
    f32x4 acc[4];
#pragma unroll
    for (int cb = 0; cb < 4; ++cb) acc[cb] = (f32x4){0.f,0.f,0.f,0.f};
    gemm_k64(acc, Ab, Bg, rt*16, lane);
    // a1B/a2B last read in stage 1 (before the barrier above) -> safe to overwrite
#pragma unroll
    for (int cb = 0; cb < 4; ++cb)
#pragma unroll
      for (int v = 0; v < 4; ++v)
        stBF(dstB, rt*16 + (lg << 2) + v, (cb << 4) + l15, acc[cb][v]);
  }
  __syncthreads();

  // ================= stage 2 =================
  {
    const float4v ge4 = *(const float4v*)(cw + 1280 + myc4);
    const float4v b54 = *(const float4v*)(bx2v + myc4);
    const float4v D1a = *(const float4v*)(cw +  768 + myc4);
    const float4v D1b = *(const float4v*)(cw +  832 + myc4);
    const float4v D1c = *(const float4v*)(cw +  896 + myc4);
    const float4v D2a = *(const float4v*)(cw +  960 + myc4);
    const float4v D2b = *(const float4v*)(cw + 1024 + myc4);
    const float4v D2c = *(const float4v*)(cw + 1088 + myc4);
    float4v b30f4[4];
#pragma unroll
    for (int mb = 0; mb < 4; ++mb)
      b30f4[mb] = *(const float4v*)(b30v + mb*16 + gc4);
    float b31r[4];
#pragma unroll
    for (int cb = 0; cb < 4; ++cb) b31r[cb] = b31v[cb*16 + l15] * LOG2E;

    // hoist W30A + W31 into NAMED registers
    DECL8(W30Ar); DECL8(W31r);
    LOAD8(W30Ar, wlds + 0);
    LOAD8(W31r,  wlds + 24576);

    for (int cc = 0; cc < 8; ++cc){
      const int p  = wave*8 + cc;
      const float px = x1[p*4], py = x1[p*4+1], pz = x1[p*4+2];
      float euR;
      { float dx = x1[l31*4]-px, dy = x1[l31*4+1]-py, dz = x1[l31*4+2]-pz;
        euR = sqrtf(dx*dx + dy*dy + dz*dz + 1e-20f); }
      const float4v ebase = D1a*px + D1b*py + D1c*pz + b54;
      // acc init = b30 + v1[p] (ch-major groups)
      float4v bv1[4];
#pragma unroll
      for (int mb = 0; mb < 4; ++mb)
        bv1[mb] = b30f4[mb] + ldBF4(a1B, p, mb*16 + gc4);
      // e2 -> myA
#pragma unroll
      for (int it = 0; it < 8; ++it){
        int q = it*4 + lg;
        float qx = x1[q*4], qy = x1[q*4+1], qz = x1[q*4+2];
        float eu = __shfl(euR, q, 64);
        float4v ev = ebase + D2a*qx + D2b*qy + D2c*qz + ge4*eu;
        ev.x = fmaxf(ev.x,0.f); ev.y = fmaxf(ev.y,0.f); ev.z = fmaxf(ev.z,0.f); ev.w = fmaxf(ev.w,0.f);
        stBF4(myA, q, myc4, ev);
      }
      // mlp3_0 (ch-major): c3 = relu(W30a*e2 + (v1[p]+b30 in acc) + v2[q]) -> myB
      f32x4 acc[2][4];
#pragma unroll
      for (int nb = 0; nb < 2; ++nb)
#pragma unroll
        for (int mb = 0; mb < 4; ++mb) acc[nb][mb] = bv1[mb];
      __builtin_amdgcn_s_setprio(1);
      GEMM_CH(acc, myA, W30Ar);
      __builtin_amdgcn_s_setprio(0);
#pragma unroll
      for (int nb = 0; nb < 2; ++nb){
        const int q   = nb*16 + l15;
        const int rb  = q << 7;
        const int swz = (q & 7) << 4;
#pragma unroll
        for (int mb = 0; mb < 4; ++mb){
          float4v v2 = ldBF4(a2B, q, mb*16 + gc4);
          f32x4 z = acc[nb][mb] + v2;
          z.x=fmaxf(z.x,0.f); z.y=fmaxf(z.y,0.f); z.z=fmaxf(z.z,0.f); z.w=fmaxf(z.w,0.f);
          uint2v u; u.x = cvtpk(z.x, z.y); u.y = cvtpk(z.z, z.w);
          *(uint2v*)(myB + (rb + ((mb*32 + lg*8) ^ swz))) = u;
        }
      }
      // mlp3_1 (pair-major): logits (bias in acc init)
      f32x4 acc2[2][4];
#pragma unroll
      for (int t = 0; t < 2; ++t)
#pragma unroll
        for (int cb = 0; cb < 4; ++cb)
          acc2[t][cb] = (f32x4){b31r[cb], b31r[cb], b31r[cb], b31r[cb]};
      __builtin_amdgcn_s_setprio(1);
      GEMM_PM(acc2, myB, W31r);
      __builtin_amdgcn_s_setprio(0);
      // no-max masked softmax (q != p) -> OUTB
      float den[4] = {0.f,0.f,0.f,0.f}, num[4] = {0.f,0.f,0.f,0.f};
#pragma unroll
      for (int t = 0; t < 2; ++t)
#pragma unroll
        for (int cb = 0; cb < 4; ++cb)
#pragma unroll
          for (int v = 0; v < 4; ++v){
            int q = t*16 + (lg<<2) + v;
            float e = exp2a(fmaxf(acc2[t][cb][v], 0.f));
            e = (q == p) ? 0.f : e;                     // mask self-pair
            den[cb] += e;
            num[cb] += e * ldBF(aggB, q, (cb<<4) + l15);
          }
#pragma unroll
      for (int cb = 0; cb < 4; ++cb){ den[cb] = red_sum(den[cb]); num[cb] = red_sum(num[cb]); }
      {
        float nv = (lg==0)?num[0]:((lg==1)?num[1]:((lg==2)?num[2]:num[3]));
        float dv = (lg==0)?den[0]:((lg==1)?den[1]:((lg==2)?den[2]:den[3]));
        outb[outb_idx(p, (lg<<4) + l15)] = nv / dv;     // all 64 lanes, 64 ch
      }
    }
  }
  __syncthreads();

  // coalesced output write (OUTB is XOR-swizzled f32)
  for (int i = tid; i < 2048; i += TPB){
    int ch = i >> 5, p = i & 31;
    out[(b*64 + ch)*S_LEN + s0 + p] = outb[outb_idx(p, ch)];
  }
}

extern "C" void kernel_launch(void* const* d_in, const int* in_sizes, int n_in,
                              void* d_out, int out_size, void* d_ws, size_t ws_size,
                              hipStream_t stream)
{
  const float* xyz1 = (const float*)d_in[0];
  const float* feat1= (const float*)d_in[1];
  const float* xyz2 = (const float*)d_in[2];
  const float* feat2= (const float*)d_in[3];
  const float* w10  = (const float*)d_in[4];
  const float* b10  = (const float*)d_in[5];
  const float* w11  = (const float*)d_in[6];
  const float* b11  = (const float*)d_in[7];
  const float* wx1  = (const float*)d_in[8];
  const float* bx1  = (const float*)d_in[9];
  const float* wx2  = (const float*)d_in[10];
  const float* bx2  = (const float*)d_in[11];
  const float* w20  = (const float*)d_in[12];
  const float* b20  = (const float*)d_in[13];
  const float* w21  = (const float*)d_in[14];
  const float* b21  = (const float*)d_in[15];
  const float* w30  = (const float*)d_in[16];
  const float* b30  = (const float*)d_in[17];
  const float* w31  = (const float*)d_in[18];
  const float* b31  = (const float*)d_in[19];

  (void)hipFuncSetAttribute(reinterpret_cast<const void*>(cvkernel),
                            hipFuncAttributeMaxDynamicSharedMemorySize, LDS_TOTAL);

  hipLaunchKernelGGL(pack_weights, dim3(64), dim3(256), 0, stream,
                     w10, w11, wx1, wx2, w20, w21, w30, w31, (unsigned char*)d_ws);
  hipLaunchKernelGGL(cvkernel, dim3(512), dim3(TPB), LDS_TOTAL, stream,
                     xyz1, feat1, xyz2, feat2,
                     b10, bx1, b11, b20, b21, bx2, b30, b31,
                     (const char*)d_ws, (float*)d_out);
}

// Round 12
// 82.147 us; speedup vs baseline: 1.4230x; 1.4230x over previous
//
#include <hip/hip_runtime.h>

// ---------------------------------------------------------------------------
// CostVolume fused kernel, R12 = R8 (measured optimum, 82.4 us).
// Established rules from R0-R11:
//  - weights must be LDS-resident, read per-use as dense ds_read_b128
//    (register-hoisting in ANY form spills: R5/R7/R9/R11 all regressed;
//    unified VGPR/AGPR budget at 2 waves/EU has no headroom)
//  - 2 blocks/CU (LDS 78.8 KB) + all-LDS weights + ch-major vectorized
//    epilogues are the winning triple (R6)
//  - no-max softmax (logits>=0, bounded), euc dedup, OUTB coalesced
//    output (R8)
//  - further VALU cuts are neutral: latency-bound at 2 waves/SIMD (R10)
// ---------------------------------------------------------------------------

typedef __attribute__((ext_vector_type(8))) short   short8;
typedef __attribute__((ext_vector_type(8))) __bf16  bf16x8;
typedef __attribute__((ext_vector_type(4))) float   f32x4;
typedef __attribute__((ext_vector_type(4))) float   float4v;
typedef __attribute__((ext_vector_type(2))) unsigned int uint2v;
typedef __attribute__((ext_vector_type(4))) unsigned int uint4v;

#define S_LEN 8192
#define TPB   256
#define LOG2E 1.4426950408889634f

// ---- workspace byte offsets (written by pack_weights) ----
#define WSO_L11   0
#define WSO_L20   8192
#define WSO_L21   24576
#define WSO_L30A  32768
#define WSO_L31   40960
#define WS_WF1    49152
#define WS_WF2    57344
#define WS_W30B   65536
#define WS_W30C   73728
#define WS_F32    81920   // 1344 f32: x-combos (6*192) + we1/ee/ge (3*64)

// ---- LDS byte offsets ----
#define OFF_W     0       // 32 KB: s1 W11@0 W20@8192 W21@24576; s2 W30A@0 W31@24576
#define OFF_OUTB  8192    // [32][64] f32 swizzled, overlays W20 slot (stage 2)
#define OFF_ACT   32768   // 4 waves x (myA 4K + myB 4K); phase A: F1B@+0, F2B@+4096
#define OFF_A1B   65536   // [32][64] bf16 swz: a1 (stage1) -> v1 (stage2)
#define OFF_A2B   69632   // [32][64] bf16 swz: a2 (stage1) -> v2 (stage2)
#define OFF_AGGB  73728   // [32][64] bf16 swz
#define OFF_X1    77824   // [32][4] f32
#define OFF_X2    78336
#define OFF_EUCB  78848   // [4][32] f32 (per-wave euc row)
#define LDS_TOTAL 79360

__device__ __forceinline__ unsigned short f2bf(float f){
  unsigned int u = __float_as_uint(f);
  u += 0x7fffu + ((u >> 16) & 1u);
  return (unsigned short)(u >> 16);
}
__device__ __forceinline__ float bf2f(unsigned short h){
  return __uint_as_float(((unsigned int)h) << 16);
}
__device__ __forceinline__ unsigned cvtpk(float lo, float hi){
  unsigned r;
  asm("v_cvt_pk_bf16_f32 %0, %1, %2" : "=v"(r) : "v"(lo), "v"(hi));
  return r;
}
__device__ __forceinline__ float exp2a(float x){
  float r; asm("v_exp_f32 %0, %1" : "=v"(r) : "v"(x)); return r;
}

// swizzled bf16 [32][64]: byte = (r*128 + c*2) ^ ((r&7)<<4)
__device__ __forceinline__ bf16x8 ldsA(const char* base, int r, int k){
  short8 a = *(const short8*)(base + ((((r << 6) + k) << 1) ^ ((r & 7) << 4)));
  return __builtin_bit_cast(bf16x8, a);
}
__device__ __forceinline__ void stBF(char* base, int r, int c, float v){
  *(unsigned short*)(base + ((((r << 6) + c) << 1) ^ ((r & 7) << 4))) = f2bf(v);
}
__device__ __forceinline__ float ldBF(const char* base, int r, int c){
  return bf2f(*(const unsigned short*)(base + ((((r << 6) + c) << 1) ^ ((r & 7) << 4))));
}
__device__ __forceinline__ void stBF4(char* base, int r, int c4, float4v v){
  uint2v u; u.x = cvtpk(v.x, v.y); u.y = cvtpk(v.z, v.w);
  *(uint2v*)(base + ((((r << 6) + c4) << 1) ^ ((r & 7) << 4))) = u;
}
// read 4 consecutive bf16 (c4 % 4 == 0) -> f32x4
__device__ __forceinline__ float4v ldBF4(const char* base, int r, int c4){
  uint2v u = *(const uint2v*)(base + ((((r << 6) + c4) << 1) ^ ((r & 7) << 4)));
  float4v f;
  f.x = bf2f((unsigned short)(u.x & 0xffffu));
  f.y = bf2f((unsigned short)(u.x >> 16));
  f.z = bf2f((unsigned short)(u.y & 0xffffu));
  f.w = bf2f((unsigned short)(u.y >> 16));
  return f;
}
// OUTB f32 [32][64], idx ^= (p&7)<<2
__device__ __forceinline__ int outb_idx(int p, int ch){
  return ((p << 6) + ch) ^ ((p & 7) << 2);
}

// pair-major K=64 GEMM over 16 rows (precompute), B-pack from global/LDS
__device__ __forceinline__ void gemm_k64(f32x4 acc[4], const char* Asrc,
                                         const char* Bp, int rbase, int lane){
  const int r  = rbase + (lane & 15);
  const int kg = (lane >> 4) << 3;
#pragma unroll
  for (int kb = 0; kb < 2; ++kb){
    bf16x8 a = ldsA(Asrc, r, kb * 32 + kg);
#pragma unroll
    for (int cb = 0; cb < 4; ++cb){
      short8 braw = *(const short8*)(Bp + (((kb << 2) + cb) * 64 + lane) * 16);
      acc[cb] = __builtin_amdgcn_mfma_f32_16x16x32_bf16(
          a, __builtin_bit_cast(bf16x8, braw), acc[cb], 0, 0, 0);
    }
  }
}

// pair-major K=64 GEMM over the wave's 32 rows, B(weights) from LDS per-use
__device__ __forceinline__ void gemm32_k64B(f32x4 acc[2][4], const char* Asrc,
                                            const char* Bp, int lane){
  const int kg = (lane >> 4) << 3;
#pragma unroll
  for (int t = 0; t < 2; ++t){
    const int r = t * 16 + (lane & 15);
#pragma unroll
    for (int kb = 0; kb < 2; ++kb){
      bf16x8 a = ldsA(Asrc, r, kb * 32 + kg);
#pragma unroll
      for (int cb = 0; cb < 4; ++cb){
        short8 braw = *(const short8*)(Bp + (((kb << 2) + cb) * 64 + lane) * 16);
        acc[t][cb] = __builtin_amdgcn_mfma_f32_16x16x32_bf16(
            a, __builtin_bit_cast(bf16x8, braw), acc[t][cb], 0, 0, 0);
      }
    }
  }
}

// ch-major K=64 GEMM: D[ch][pair], W(A-operand) from LDS pack, acts from LDS
__device__ __forceinline__ void gemm_chL(f32x4 acc[2][4], const char* act,
                                         const char* Wp, int l15, int kg, int lane){
#pragma unroll
  for (int kb = 0; kb < 2; ++kb){
    bf16x8 W[4];
#pragma unroll
    for (int mb = 0; mb < 4; ++mb)
      W[mb] = __builtin_bit_cast(bf16x8,
          *(const short8*)(Wp + (((kb << 2) + mb) * 64 + lane) * 16));
#pragma unroll
    for (int nb = 0; nb < 2; ++nb){
      bf16x8 bfrag = ldsA(act, nb * 16 + l15, kb * 32 + kg);
#pragma unroll
      for (int mb = 0; mb < 4; ++mb)
        acc[nb][mb] = __builtin_amdgcn_mfma_f32_16x16x32_bf16(
            W[mb], bfrag, acc[nb][mb], 0, 0, 0);
    }
  }
}

// ch-major epilogue: relu(acc+bias) -> 8B-vectorized bf16 stores
__device__ __forceinline__ void store_ch(char* dst, f32x4 acc[2][4],
                                         const float4v bias4[4], int l15, int g){
#pragma unroll
  for (int nb = 0; nb < 2; ++nb){
    const int row = nb * 16 + l15;
    const int rb  = row << 7;
    const int swz = (row & 7) << 4;
#pragma unroll
    for (int mb = 0; mb < 4; ++mb){
      f32x4 z = acc[nb][mb] + bias4[mb];
      z.x=fmaxf(z.x,0.f); z.y=fmaxf(z.y,0.f); z.z=fmaxf(z.z,0.f); z.w=fmaxf(z.w,0.f);
      uint2v u; u.x = cvtpk(z.x, z.y); u.y = cvtpk(z.z, z.w);
      *(uint2v*)(dst + (rb + ((mb * 32 + g * 8) ^ swz))) = u;
    }
  }
}

__device__ __forceinline__ float red_sum(float x){
  x += __shfl_xor(x, 16, 64);
  x += __shfl_xor(x, 32, 64);
  return x;
}

__global__ void pack_weights(const float* __restrict__ w10, const float* __restrict__ w11,
                             const float* __restrict__ wx1, const float* __restrict__ wx2,
                             const float* __restrict__ w20, const float* __restrict__ w21,
                             const float* __restrict__ w30, const float* __restrict__ w31,
                             unsigned char* __restrict__ ws)
{
  for (int i = blockIdx.x * blockDim.x + threadIdx.x; i < 42304;
       i += gridDim.x * blockDim.x){
    if (i < 40960){
      const float* src; int stride, coff, e;
      if      (i <  4096){ src = w11; stride =  64; coff =   0; e = i;         }
      else if (i < 12288){ src = w20; stride = 128; coff =   0; e = i -  4096; }
      else if (i < 16384){ src = w21; stride =  64; coff =   0; e = i - 12288; }
      else if (i < 20480){ src = w30; stride = 192; coff =   0; e = i - 16384; }
      else if (i < 24576){ src = w31; stride =  64; coff =   0; e = i - 20480; }
      else if (i < 28672){ src = w10; stride = 138; coff =  10; e = i - 24576; }
      else if (i < 32768){ src = w10; stride = 138; coff =  74; e = i - 28672; }
      else if (i < 36864){ src = w30; stride = 192; coff =  64; e = i - 32768; }
      else               { src = w30; stride = 192; coff = 128; e = i - 36864; }
      int j = e & 7, lane = (e >> 3) & 63, cb = (e >> 9) & 3, kb = e >> 11;
      int k = kb * 32 + ((lane >> 4) << 3) + j;
      int o = cb * 16 + (lane & 15);
      float val = src[o * stride + coff + k];
      // pre-scale logit-layer weights by log2(e): exp(x)=exp2(x*LOG2E)
      if ((i >= 12288 && i < 16384) || (i >= 20480 && i < 24576)) val *= LOG2E;
      ((unsigned short*)ws)[i] = f2bf(val);
    } else {
      int f = i - 40960; float v;
      if (f < 1152){
        int grp = f / 192, rem = f % 192, d = rem >> 6, o = rem & 63;
        if      (grp == 0) v = w10[o*138 + d]     - w10[o*138 + 6 + d];
        else if (grp == 1) v = w10[o*138 + 3 + d] + w10[o*138 + 6 + d];
        else if (grp == 2) v = wx1[o*10 + d]      - wx1[o*10 + 6 + d];
        else if (grp == 3) v = wx1[o*10 + 3 + d]  + wx1[o*10 + 6 + d];
        else if (grp == 4) v = wx2[o*10 + d]      - wx2[o*10 + 6 + d];
        else               v = wx2[o*10 + 3 + d]  + wx2[o*10 + 6 + d];
      }
      else if (f < 1216) v = w10[(f - 1152)*138 + 9];
      else if (f < 1280) v = wx1[(f - 1216)*10  + 9];
      else               v = wx2[(f - 1280)*10  + 9];
      ((float*)(ws + WS_F32))[f] = v;
    }
  }
}

__global__ __launch_bounds__(TPB, 2) void cvkernel(
    const float* __restrict__ xyz1, const float* __restrict__ feat1,
    const float* __restrict__ xyz2, const float* __restrict__ feat2,
    const float* __restrict__ b10v, const float* __restrict__ bx1v,
    const float* __restrict__ b11v, const float* __restrict__ b20v,
    const float* __restrict__ b21v, const float* __restrict__ bx2v,
    const float* __restrict__ b30v, const float* __restrict__ b31v,
    const char*  __restrict__ ws,   float* __restrict__ out)
{
  extern __shared__ __align__(16) char smem[];
  const int tid  = threadIdx.x;
  const int lane = tid & 63;
  const int wave = tid >> 6;
  const int l15  = lane & 15;
  const int lg   = lane >> 4;
  const int kg   = lg << 3;
  const int tile = blockIdx.x;
  const int b    = tile >> 8;
  const int s0   = (tile & 255) << 5;

  float* x1   = (float*)(smem + OFF_X1);
  float* x2   = (float*)(smem + OFF_X2);
  char*  a1B  = smem + OFF_A1B;
  char*  a2B  = smem + OFF_A2B;
  char*  aggB = smem + OFF_AGGB;
  char*  wlds = smem + OFF_W;
  float* outb = (float*)(smem + OFF_OUTB);
  float* eucb = (float*)(smem + OFF_EUCB) + wave * 32;
  const float* cw = (const float*)(ws + WS_F32);

  char* myA = smem + OFF_ACT + wave * 8192;
  char* myB = myA + 4096;

  // ======== phase A: stage weights (32 KB), inputs, X ========
  { const uint4v* src = (const uint4v*)ws;            // L11+L20+L21
    uint4v*       dst = (uint4v*)wlds;
    for (int i = tid; i < 2048; i += TPB) dst[i] = src[i]; }
  if (tid < 32){
#pragma unroll
    for (int d = 0; d < 3; ++d) x1[tid*4+d] = xyz1[(b*3+d)*S_LEN + s0 + tid];
    x1[tid*4+3] = 0.f;
  } else if (tid < 64){
    int p = tid - 32;
#pragma unroll
    for (int d = 0; d < 3; ++d) x2[p*4+d] = xyz2[(b*3+d)*S_LEN + s0 + p];
    x2[p*4+3] = 0.f;
  }
  for (int i = tid; i < 2048; i += TPB){                // F1B/F2B into ACT region
    int ch = i >> 5, p = i & 31;
    stBF(smem + OFF_ACT,        p, ch, feat1[(b*64+ch)*S_LEN + s0 + p]);
    stBF(smem + OFF_ACT + 4096, p, ch, feat2[(b*64+ch)*S_LEN + s0 + p]);
  }
  __syncthreads();

  // per-point precompute: a1 = Wf1*f1 + x-part, a2 = Wf2*f2 + x-part (bf16 out)
  {
    const char* Ab  = (wave < 2) ? (smem + OFF_ACT) : (smem + OFF_ACT + 4096);
    const char* Bg  = ws + ((wave < 2) ? WS_WF1 : WS_WF2);
    char* dstB      = (wave < 2) ? a1B : a2B;
    const float* cc = (wave < 2) ? cw : cw + 192;
    const float* xs = (wave < 2) ? x1 : x2;
    const int rt    = wave & 1;
    f32x4 acc[4];
#pragma unroll
    for (int cb = 0; cb < 4; ++cb) acc[cb] = (f32x4){0.f,0.f,0.f,0.f};
    gemm_k64(acc, Ab, Bg, rt * 16, lane);
#pragma unroll
    for (int cb = 0; cb < 4; ++cb){
      int col = (cb << 4) + l15;
      float c0 = cc[col], c1 = cc[64+col], c2 = cc[128+col];
#pragma unroll
      for (int v = 0; v < 4; ++v){
        int row = rt*16 + (lg << 2) + v;
        float val = acc[cb][v] + c0*xs[row*4] + c1*xs[row*4+1] + c2*xs[row*4+2];
        stBF(dstB, row, col, val);
      }
    }
  }
  __syncthreads();

  const int myc4 = l15 << 2;
  const int gc4  = lg << 2;

  // ================= stage 1 =================
  {
    const float4v we4 = *(const float4v*)(cw + 1152 + myc4);
    const float4v ee4 = *(const float4v*)(cw + 1216 + myc4);
    const float4v b04 = *(const float4v*)(b10v + myc4);
    const float4v b14 = *(const float4v*)(bx1v + myc4);
    const float4v C1a = *(const float4v*)(cw + 384 + myc4);
    const float4v C1b = *(const float4v*)(cw + 448 + myc4);
    const float4v C1c = *(const float4v*)(cw + 512 + myc4);
    const float4v C2a = *(const float4v*)(cw + 576 + myc4);
    const float4v C2b = *(const float4v*)(cw + 640 + myc4);
    const float4v C2c = *(const float4v*)(cw + 704 + myc4);
    float4v b11f4[4], b20f4[4];
#pragma unroll
    for (int mb = 0; mb < 4; ++mb){
      b11f4[mb] = *(const float4v*)(b11v + mb*16 + gc4);
      b20f4[mb] = *(const float4v*)(b20v + mb*16 + gc4);
    }
    float b21r[4];
#pragma unroll
    for (int cb = 0; cb < 4; ++cb) b21r[cb] = b21v[cb*16 + l15] * LOG2E;

    for (int cc = 0; cc < 8; ++cc){
      const int p  = wave*8 + cc;
      const float px = x1[p*4], py = x1[p*4+1], pz = x1[p*4+2];
      // euc dedup: lanes 0-31 compute the 32 pair distances once
      if (lane < 32){
        float dx = x2[lane*4]-px, dy = x2[lane*4+1]-py, dz = x2[lane*4+2]-pz;
        eucb[lane] = sqrtf(dx*dx + dy*dy + dz*dz + 1e-20f);
      }
      const float4v hbase = ldBF4(a1B, p, myc4) + b04;
      const float4v ebase = C1a*px + C1b*py + C1c*pz + b14;
      // build h1 -> myA, e -> myB
#pragma unroll
      for (int it = 0; it < 8; ++it){
        int q = it*4 + lg;
        float qx = x2[q*4], qy = x2[q*4+1], qz = x2[q*4+2];
        float eu = eucb[q];
        float4v A2 = ldBF4(a2B, q, myc4);
        float4v hv = hbase + A2 + we4*eu;
        float4v ev = ebase + C2a*qx + C2b*qy + C2c*qz + ee4*eu;
        hv.x = fmaxf(hv.x,0.f); hv.y = fmaxf(hv.y,0.f); hv.z = fmaxf(hv.z,0.f); hv.w = fmaxf(hv.w,0.f);
        ev.x = fmaxf(ev.x,0.f); ev.y = fmaxf(ev.y,0.f); ev.z = fmaxf(ev.z,0.f); ev.w = fmaxf(ev.w,0.f);
        stBF4(myA, q, myc4, hv);
        stBF4(myB, q, myc4, ev);
      }
      // mlp1_1 (ch-major): h2 = relu(W11*h1 + b11) -> myA (h1 dead)
      f32x4 acc[2][4];
#pragma unroll
      for (int nb = 0; nb < 2; ++nb)
#pragma unroll
        for (int mb = 0; mb < 4; ++mb) acc[nb][mb] = (f32x4){0.f,0.f,0.f,0.f};
      __builtin_amdgcn_s_setprio(1);
      gemm_chL(acc, myA, wlds + 0, l15, kg, lane);
      __builtin_amdgcn_s_setprio(0);
      store_ch(myA, acc, b11f4, l15, lg);
      // mlp2_0 (ch-major, K=128): [e(myB); h2(myA)] -> myB (e dead)
#pragma unroll
      for (int nb = 0; nb < 2; ++nb)
#pragma unroll
        for (int mb = 0; mb < 4; ++mb) acc[nb][mb] = (f32x4){0.f,0.f,0.f,0.f};
      __builtin_amdgcn_s_setprio(1);
      gemm_chL(acc, myB, wlds + 8192,  l15, kg, lane);
      gemm_chL(acc, myA, wlds + 16384, l15, kg, lane);
      __builtin_amdgcn_s_setprio(0);
      store_ch(myB, acc, b20f4, l15, lg);
      // mlp2_1 (pair-major): logits in regs (weights pre-scaled by log2e)
      f32x4 acc2[2][4];
#pragma unroll
      for (int t = 0; t < 2; ++t)
#pragma unroll
        for (int cb = 0; cb < 4; ++cb) acc2[t][cb] = (f32x4){0.f,0.f,0.f,0.f};
      __builtin_amdgcn_s_setprio(1);
      gemm32_k64B(acc2, myB, wlds + 24576, lane);
      __builtin_amdgcn_s_setprio(0);
      // no-max softmax over 32 q + aggregation (h2 from myA); logits >= 0 bounded
      float den[4] = {0.f,0.f,0.f,0.f}, num[4] = {0.f,0.f,0.f,0.f};
#pragma unroll
      for (int t = 0; t < 2; ++t)
#pragma unroll
        for (int cb = 0; cb < 4; ++cb)
#pragma unroll
          for (int v = 0; v < 4; ++v){
            float l = fmaxf(acc2[t][cb][v] + b21r[cb], 0.f);
            float e = exp2a(l);
            den[cb] += e;
            num[cb] += e * ldBF(myA, t*16 + (lg<<2) + v, (cb<<4) + l15);
          }
#pragma unroll
      for (int cb = 0; cb < 4; ++cb){ den[cb] = red_sum(den[cb]); num[cb] = red_sum(num[cb]); }
      {
        float nv = (lg==0)?num[0]:((lg==1)?num[1]:((lg==2)?num[2]:num[3]));
        float dv = (lg==0)?den[0]:((lg==1)?den[1]:((lg==2)?den[2]:den[3]));
        stBF(aggB, p, (lg<<4) + l15, nv / dv);   // all 64 lanes: 64 channels
      }
    }
  }
  __syncthreads();

  // ======== phase C: restage f1, swap W packs, v1/v2 precompute ========
  for (int i = tid; i < 2048; i += TPB){                // f1 -> ACT+0
    int ch = i >> 5, p = i & 31;
    stBF(smem + OFF_ACT, p, ch, feat1[(b*64+ch)*S_LEN + s0 + p]);
  }
  { const uint4v* sA = (const uint4v*)(ws + WSO_L30A);  // W30A -> slot 0
    const uint4v* sB = (const uint4v*)(ws + WSO_L31);   // W31  -> slot 24576
    uint4v* dA = (uint4v*)(wlds);
    uint4v* dB = (uint4v*)(wlds + 24576);
    for (int i = tid; i < 512; i += TPB){ dA[i] = sA[i]; dB[i] = sB[i]; } }
  __syncthreads();
  {
    const char* Ab = (wave < 2) ? (smem + OFF_ACT) : aggB;
    const char* Bg = ws + ((wave < 2) ? WS_W30B : WS_W30C);
    char* dstB     = (wave < 2) ? a1B : a2B;            // v1 / v2
    const int rt   = wave & 1;
    f32x4 acc[4];
#pragma unroll
    for (int cb = 0; cb < 4; ++cb) acc[cb] = (f32x4){0.f,0.f,0.f,0.f};
    gemm_k64(acc, Ab, Bg, rt*16, lane);
    __syncthreads();   // all reads of a1B/a2B done before overwrite
#pragma unroll
    for (int cb = 0; cb < 4; ++cb)
#pragma unroll
      for (int v = 0; v < 4; ++v)
        stBF(dstB, rt*16 + (lg << 2) + v, (cb << 4) + l15, acc[cb][v]);
  }
  __syncthreads();

  // ================= stage 2 =================
  {
    const float4v ge4 = *(const float4v*)(cw + 1280 + myc4);
    const float4v b54 = *(const float4v*)(bx2v + myc4);
    const float4v D1a = *(const float4v*)(cw +  768 + myc4);
    const float4v D1b = *(const float4v*)(cw +  832 + myc4);
    const float4v D1c = *(const float4v*)(cw +  896 + myc4);
    const float4v D2a = *(const float4v*)(cw +  960 + myc4);
    const float4v D2b = *(const float4v*)(cw + 1024 + myc4);
    const float4v D2c = *(const float4v*)(cw + 1088 + myc4);
    float4v b30f4[4];
#pragma unroll
    for (int mb = 0; mb < 4; ++mb)
      b30f4[mb] = *(const float4v*)(b30v + mb*16 + gc4);
    float b31r[4];
#pragma unroll
    for (int cb = 0; cb < 4; ++cb) b31r[cb] = b31v[cb*16 + l15] * LOG2E;

    for (int cc = 0; cc < 8; ++cc){
      const int p  = wave*8 + cc;
      const float px = x1[p*4], py = x1[p*4+1], pz = x1[p*4+2];
      if (lane < 32){
        float dx = x1[lane*4]-px, dy = x1[lane*4+1]-py, dz = x1[lane*4+2]-pz;
        eucb[lane] = sqrtf(dx*dx + dy*dy + dz*dz + 1e-20f);
      }
      const float4v ebase = D1a*px + D1b*py + D1c*pz + b54;
      float4v v1f4[4];
#pragma unroll
      for (int mb = 0; mb < 4; ++mb)
        v1f4[mb] = ldBF4(a1B, p, mb*16 + gc4);
      // e2 -> myA
#pragma unroll
      for (int it = 0; it < 8; ++it){
        int q = it*4 + lg;
        float qx = x1[q*4], qy = x1[q*4+1], qz = x1[q*4+2];
        float eu = eucb[q];
        float4v ev = ebase + D2a*qx + D2b*qy + D2c*qz + ge4*eu;
        ev.x = fmaxf(ev.x,0.f); ev.y = fmaxf(ev.y,0.f); ev.z = fmaxf(ev.z,0.f); ev.w = fmaxf(ev.w,0.f);
        stBF4(myA, q, myc4, ev);
      }
      // mlp3_0 (ch-major): c3 = relu(W30a*e2 + v1[p] + v2[q] + b30) -> myB
      f32x4 acc[2][4];
#pragma unroll
      for (int nb = 0; nb < 2; ++nb)
#pragma unroll
        for (int mb = 0; mb < 4; ++mb) acc[nb][mb] = (f32x4){0.f,0.f,0.f,0.f};
      __builtin_amdgcn_s_setprio(1);
      gemm_chL(acc, myA, wlds + 0, l15, kg, lane);
      __builtin_amdgcn_s_setprio(0);
#pragma unroll
      for (int nb = 0; nb < 2; ++nb){
        const int q   = nb*16 + l15;
        const int rb  = q << 7;
        const int swz = (q & 7) << 4;
#pragma unroll
        for (int mb = 0; mb < 4; ++mb){
          float4v v2 = ldBF4(a2B, q, mb*16 + gc4);
          f32x4 z = acc[nb][mb] + v1f4[mb] + v2 + b30f4[mb];
          z.x=fmaxf(z.x,0.f); z.y=fmaxf(z.y,0.f); z.z=fmaxf(z.z,0.f); z.w=fmaxf(z.w,0.f);
          uint2v u; u.x = cvtpk(z.x, z.y); u.y = cvtpk(z.z, z.w);
          *(uint2v*)(myB + (rb + ((mb*32 + lg*8) ^ swz))) = u;
        }
      }
      // mlp3_1 (pair-major): logits
      f32x4 acc2[2][4];
#pragma unroll
      for (int t = 0; t < 2; ++t)
#pragma unroll
        for (int cb = 0; cb < 4; ++cb) acc2[t][cb] = (f32x4){0.f,0.f,0.f,0.f};
      __builtin_amdgcn_s_setprio(1);
      gemm32_k64B(acc2, myB, wlds + 24576, lane);
      __builtin_amdgcn_s_setprio(0);
      // no-max masked softmax (q != p) -> OUTB
      float den[4] = {0.f,0.f,0.f,0.f}, num[4] = {0.f,0.f,0.f,0.f};
#pragma unroll
      for (int t = 0; t < 2; ++t)
#pragma unroll
        for (int cb = 0; cb < 4; ++cb)
#pragma unroll
          for (int v = 0; v < 4; ++v){
            int q = t*16 + (lg<<2) + v;
            float l = fmaxf(acc2[t][cb][v] + b31r[cb], 0.f);
            float e = exp2a(l);
            e = (q == p) ? 0.f : e;                     // mask self-pair
            den[cb] += e;
            num[cb] += e * ldBF(aggB, q, (cb<<4) + l15);
          }
#pragma unroll
      for (int cb = 0; cb < 4; ++cb){ den[cb] = red_sum(den[cb]); num[cb] = red_sum(num[cb]); }
      {
        float nv = (lg==0)?num[0]:((lg==1)?num[1]:((lg==2)?num[2]:num[3]));
        float dv = (lg==0)?den[0]:((lg==1)?den[1]:((lg==2)?den[2]:den[3]));
        outb[outb_idx(p, (lg<<4) + l15)] = nv / dv;     // all 64 lanes, 64 ch
      }
    }
  }
  __syncthreads();

  // coalesced output write (OUTB is XOR-swizzled f32)
  for (int i = tid; i < 2048; i += TPB){
    int ch = i >> 5, p = i & 31;
    out[(b*64 + ch)*S_LEN + s0 + p] = outb[outb_idx(p, ch)];
  }
}

extern "C" void kernel_launch(void* const* d_in, const int* in_sizes, int n_in,
                              void* d_out, int out_size, void* d_ws, size_t ws_size,
                              hipStream_t stream)
{
  const float* xyz1 = (const float*)d_in[0];
  const float* feat1= (const float*)d_in[1];
  const float* xyz2 = (const float*)d_in[2];
  const float* feat2= (const float*)d_in[3];
  const float* w10  = (const float*)d_in[4];
  const float* b10  = (const float*)d_in[5];
  const float* w11  = (const float*)d_in[6];
  const float* b11  = (const float*)d_in[7];
  const float* wx1  = (const float*)d_in[8];
  const float* bx1  = (const float*)d_in[9];
  const float* wx2  = (const float*)d_in[10];
  const float* bx2  = (const float*)d_in[11];
  const float* w20  = (const float*)d_in[12];
  const float* b20  = (const float*)d_in[13];
  const float* w21  = (const float*)d_in[14];
  const float* b21  = (const float*)d_in[15];
  const float* w30  = (const float*)d_in[16];
  const float* b30  = (const float*)d_in[17];
  const float* w31  = (const float*)d_in[18];
  const float* b31  = (const float*)d_in[19];

  (void)hipFuncSetAttribute(reinterpret_cast<const void*>(cvkernel),
                            hipFuncAttributeMaxDynamicSharedMemorySize, LDS_TOTAL);

  hipLaunchKernelGGL(pack_weights, dim3(64), dim3(256), 0, stream,
                     w10, w11, wx1, wx2, w20, w21, w30, w31, (unsigned char*)d_ws);
  hipLaunchKernelGGL(cvkernel, dim3(512), dim3(TPB), LDS_TOTAL, stream,
                     xyz1, feat1, xyz2, feat2,
                     b10, bx1, b11, b20, b21, bx2, b30, b31,
                     (const char*)d_ws, (float*)d_out);
}